// Round 21
// baseline (210.515 us; speedup 1.0000x reference)
//
#include <hip/hip_runtime.h>

// Generalized Lotka-Volterra, RK4, D=64, batch 2048, 255 steps,
// trajectory out (batch, 256, 64) fp32.
//
// = R20 i8 kernel (169us) + HALF-SPLIT delivery with exact-int recombine:
//   - lanes 0-31 read x-dwords [0,8), lanes 32-63 read [8,16):
//     2 uniform-per-half ds_read_b128 = 32 B/lane/feval (half of R20).
//   - lane L (pL = L&31, h = L>>5) holds rows pL and pL+32, columns
//     [32h, 32h+32), i8-quantized per row: 16 v_dot4_i32_i8 (MAC count
//     invariant), two int partials accA (row pL), accB (row pL+32).
//   - exchange ONE int via v_permlane32_swap_b32 (convention probed once,
//     R13/R17-verified): send = h ? accA : accB (what partner's row needs),
//     own = h ? accB : accA; total = own + received.
//   - INTEGER partials -> recombination is EXACT: result bit-identical to
//     R20 (absmax must be exactly 0.00390625; deviation = swap bug).
// Unlike R17's f16 split (+60cyc select/bitcast storm), the plumbing here
// is 4 VALU ops. DS return floor: 2.09M fevals x 2KB / 69 TB/s ~= 62us;
// VALU becomes the binder (~140 cyc/feval) -> predicted 140-158us.
//
// Carried R19/R20 machinery: per-wave-FIFO ordering (compile-order barrier
// only, no lgkmcnt drain — R20-verified on gfx950), i8 x-broadcast via
// 2xDPP+or merge + shadow-slot ds_write, per-row-scaled i8 E, exact fp32
// diagonal/growth, waves_per_eu(2,2) + per-iteration pins (VGPR 88).

constexpr int D   = 64;   // state dimension == wavefront size
constexpr int NT  = 256;  // trajectory length (255 RK4 steps)
constexpr int WPB = 4;    // waves (= batch elements) per block

typedef unsigned u32x2 __attribute__((ext_vector_type(2)));

__device__ __forceinline__ uint32_t dpp_xor1_u(uint32_t v) {   // quad_perm [1,0,3,2]
    return (uint32_t)__builtin_amdgcn_update_dpp(0, (int)v, 0xB1, 0xF, 0xF, true);
}
__device__ __forceinline__ uint32_t dpp_xor2_u(uint32_t v) {   // quad_perm [2,3,0,1]
    return (uint32_t)__builtin_amdgcn_update_dpp(0, (int)v, 0x4E, 0xF, 0xF, true);
}
// acc += dot4(i8x4, i8x4) — signed 8-bit dot product, int32 accumulate.
__device__ __forceinline__ int dot4(int acc, uint32_t e, uint32_t x) {
#if __has_builtin(__builtin_amdgcn_sdot4)
    return __builtin_amdgcn_sdot4((int)e, (int)x, acc, false);
#else
    asm("v_dot4_i32_i8 %0, %1, %2, %0" : "+v"(acc) : "v"(e), "v"(x));
    return acc;
#endif
}
__device__ __forceinline__ u32x2 plswap(uint32_t v) {
    return __builtin_amdgcn_permlane32_swap(v, v, false, false);
}

// f(xt) = xt * (r - xt + E@xt); i8 half-split broadcast, exact-int combine.
#define FEVAL(XT, RES)                                                        \
    do {                                                                      \
        const float xt_ = (XT);                                               \
        const uint32_t q_  = (uint32_t)fmaf(xt_, 127.0f, 0.5f);               \
        const uint32_t t1_ = q_  | (dpp_xor1_u(q_)  << 8);                    \
        const uint32_t t2_ = t1_ | (dpp_xor2_u(t1_) << 16);                   \
        wbuf[waddr] = t2_;                                /* 1 ds_write */    \
        asm volatile("" ::: "memory");                    /* order only  */   \
        const uint4 v0_ = *reinterpret_cast<const uint4*>(rbuf);              \
        const uint4 v1_ = *reinterpret_cast<const uint4*>(rbuf + 4);          \
        int aA0 = 0, aA1 = 0, aB0 = 0, aB1 = 0;                               \
        aA0 = dot4(aA0, eqA[0], v0_.x);                                       \
        aB0 = dot4(aB0, eqB[0], v0_.x);                                       \
        aA1 = dot4(aA1, eqA[1], v0_.y);                                       \
        aB1 = dot4(aB1, eqB[1], v0_.y);                                       \
        aA0 = dot4(aA0, eqA[2], v0_.z);                                       \
        aB0 = dot4(aB0, eqB[2], v0_.z);                                       \
        aA1 = dot4(aA1, eqA[3], v0_.w);                                       \
        aB1 = dot4(aB1, eqB[3], v0_.w);                                       \
        aA0 = dot4(aA0, eqA[4], v1_.x);                                       \
        aB0 = dot4(aB0, eqB[4], v1_.x);                                       \
        aA1 = dot4(aA1, eqA[5], v1_.y);                                       \
        aB1 = dot4(aB1, eqB[5], v1_.y);                                       \
        aA0 = dot4(aA0, eqA[6], v1_.z);                                       \
        aB0 = dot4(aB0, eqB[6], v1_.z);                                       \
        aA1 = dot4(aA1, eqA[7], v1_.w);                                       \
        aB1 = dot4(aB1, eqB[7], v1_.w);                                       \
        const int accA_ = aA0 + aA1;        /* row pL,   cols [32h,32h+32) */ \
        const int accB_ = aB0 + aB1;        /* row pL+32, same cols        */ \
        const int send_ = hi ? accA_ : accB_;   /* partner's row needs it  */ \
        const int own_  = hi ? accB_ : accA_;   /* my row, my cols         */ \
        const u32x2 sw_ = plswap((uint32_t)send_);                            \
        const int recv_ = (int)(xIsPartner ? sw_.x : sw_.y);                  \
        const float cp_ = (float)(own_ + recv_) * scl;                        \
        RES = xt_ * ((ri + cp_) - xt_);                                       \
    } while (0)

// Per-iteration residency pin (R14-verified recipe).
#define PIN8(ARR)                                                             \
    asm volatile("" : "+v"(ARR[0]), "+v"(ARR[1]), "+v"(ARR[2]),               \
                      "+v"(ARR[3]), "+v"(ARR[4]), "+v"(ARR[5]),               \
                      "+v"(ARR[6]), "+v"(ARR[7]))

__global__ __launch_bounds__(WPB * 64)
__attribute__((amdgpu_waves_per_eu(2, 2)))
void glv_rk4_kernel(const float* __restrict__ x0,
                    const float* __restrict__ r,
                    const float* __restrict__ A,
                    const float* __restrict__ tgrid,
                    float* __restrict__ out)
{
    const int lane = threadIdx.x & 63;
    const int wid  = threadIdx.x >> 6;
    const int b    = blockIdx.x * WPB + wid;   // batch element for this wave
    const int pL   = lane & 31;
    const bool hi  = (lane >= 32);             // column-half owned by lane

    // Per-wave broadcast buffer: 16 real dwords (64 x i8) + 48 shadow.
    __shared__ uint32_t xq[WPB][64];
    uint32_t* const wbuf = &xq[wid][0];
    const int waddr = (lane >> 2) + (lane & 3) * 16;  // shadow for lane%4 != 0
    uint32_t* const rbuf = wbuf + (hi ? 8 : 0);       // own half's dwords

    // Probe permlane32_swap convention once (wave-uniform).
    const u32x2 pr = plswap((uint32_t)lane);
    const bool xIsPartner =
        (__builtin_amdgcn_readfirstlane((int)pr.x) == 32);

    // Rows rA = pL and rB = pL+32 of E = A + I: full-row max (for per-row
    // scale), keep own column-half [cb, cb+32), quantize i8.
    const int rA = pL, rB = pL + 32;
    const int cb = hi ? 32 : 0;
    float evA[32], evB[32];
    float rmA = 1e-30f, rmB = 1e-30f;
#pragma unroll
    for (int j = 0; j < D; j += 4) {
        const float4 va = *reinterpret_cast<const float4*>(A + rA * D + j);
        const float4 vb = *reinterpret_cast<const float4*>(A + rB * D + j);
        float a[4] = {va.x, va.y, va.z, va.w};
        float c[4] = {vb.x, vb.y, vb.z, vb.w};
#pragma unroll
        for (int u = 0; u < 4; ++u) {
            if (j + u == rA) a[u] += 1.0f;     // E = A + I
            if (j + u == rB) c[u] += 1.0f;
            rmA = fmaxf(rmA, fabsf(a[u]));
            rmB = fmaxf(rmB, fabsf(c[u]));
            if (j + u >= cb && j + u < cb + 32) {
                evA[j + u - cb] = a[u];
                evB[j + u - cb] = c[u];
            }
        }
    }
    const float qiA = 127.0f / rmA, qiB = 127.0f / rmB;
    // My row = lane: h=0 -> rA, h=1 -> rB; scale matches the row I output.
    const float scl = (hi ? rmB : rmA) * (1.0f / (127.0f * 127.0f));

    uint32_t eqA[8], eqB[8];
#pragma unroll
    for (int J = 0; J < 8; ++J) {
        const int a0 = (int)rintf(evA[4 * J + 0] * qiA);
        const int a1 = (int)rintf(evA[4 * J + 1] * qiA);
        const int a2 = (int)rintf(evA[4 * J + 2] * qiA);
        const int a3 = (int)rintf(evA[4 * J + 3] * qiA);
        eqA[J] = (uint32_t)(a0 & 0xFF) | ((uint32_t)(a1 & 0xFF) << 8) |
                 ((uint32_t)(a2 & 0xFF) << 16) | ((uint32_t)(a3 & 0xFF) << 24);
        const int b0_ = (int)rintf(evB[4 * J + 0] * qiB);
        const int b1_ = (int)rintf(evB[4 * J + 1] * qiB);
        const int b2_ = (int)rintf(evB[4 * J + 2] * qiB);
        const int b3_ = (int)rintf(evB[4 * J + 3] * qiB);
        eqB[J] = (uint32_t)(b0_ & 0xFF) | ((uint32_t)(b1_ & 0xFF) << 8) |
                 ((uint32_t)(b2_ & 0xFF) << 16) | ((uint32_t)(b3_ & 0xFF) << 24);
    }

    const float ri = r[lane];                  // lane owns component `lane`
    const float dt = tgrid[1] - tgrid[0];
    const float h2 = 0.5f * dt;
    const float h6 = dt * (1.0f / 6.0f);

    float x = x0[(size_t)b * D + lane];

    float* o = out + (size_t)b * NT * D + lane;
    *o = x; o += D;                            // t = 0 is x0

    for (int t = 1; t < NT; ++t) {
        PIN8(eqA); PIN8(eqB);                  // keep E in arch VGPRs
        float k1, k2, k3, k4;
        FEVAL(x, k1);
        FEVAL(fmaf(h2, k1, x), k2);
        FEVAL(fmaf(h2, k2, x), k3);
        FEVAL(fmaf(dt, k3, x), k4);
        x = fmaf(h6, (k1 + k4) + 2.0f * (k2 + k3), x);
        *o = x; o += D;                        // coalesced 256 B/wave store
    }
}

extern "C" void kernel_launch(void* const* d_in, const int* in_sizes, int n_in,
                              void* d_out, int out_size, void* d_ws, size_t ws_size,
                              hipStream_t stream) {
    const float* x0    = (const float*)d_in[0];
    const float* r     = (const float*)d_in[1];
    const float* A     = (const float*)d_in[2];
    const float* tgrid = (const float*)d_in[3];
    float* out         = (float*)d_out;

    const int batch = in_sizes[0] / D;          // 2048
    dim3 grid(batch / WPB);                     // 512 blocks
    dim3 block(WPB * 64);                       // 256 threads = 4 waves

    glv_rk4_kernel<<<grid, block, 0, stream>>>(x0, r, A, tgrid, out);
}

// Round 22
// 169.620 us; speedup vs baseline: 1.2411x; 1.2411x over previous
//
#include <hip/hip_runtime.h>

// Generalized Lotka-Volterra, RK4, D=64, batch 2048, 255 steps,
// trajectory out (batch, 256, 64) fp32.
//
// FINAL = round-20 kernel (best measured: 169us bench / 196us rocprof,
// absmax 3.9e-3 vs 2e-2 threshold). 21-round closure argument:
//   - delivery precision ladder (f32->f16->i8 LDS broadcast): 477->249->169us
//   - lgkmcnt(0) drain -> per-wave DS FIFO ordering (order-only barrier): +9%
//   - cross-lane redistribution (readlane R14, permlane f32/f16/int R13/R17/
//     R21): ALL regressed — cross-lane-via-VALU costs 2-8x its instruction
//     count on gfx950; uniform ds_read broadcast wins.
//   - MFMA formulation: closed at 270us (128 waves = parallelism-starved;
//     co-residency null R16, ILP null R11).
//   - Remaining slack: VALU 62% / LDS-return 63% — the serial
//     pack->write->read->dot chain with the structural 2 waves/SIMD cap
//     (batch = 2048 waves). Three targeted attacks regressed.
//
// Design: one wave per batch element. E = A + I quantized i8 per-row
// (scl = rowmax/127^2) in 16 VGPRs; x broadcast as i8 (q = round(127x),
// x in (0,1]): 2x DPP-or merges 4 lanes' bytes/dword, 1 ds_write_b32/lane
// (never-read shadow slots for lane%4 != 0), 4 uniform ds_read_b128 =
// 64 B/lane/feval, 16 v_dot4_i32_i8 int32-accumulate, one scale at the
// end. Diagonal -x and growth r exact fp32: f = x*((r - x) + E@x).
// waves_per_eu(2,2) + per-iteration pins keep eq[] in arch VGPRs.

constexpr int D   = 64;   // state dimension == wavefront size
constexpr int NT  = 256;  // trajectory length (255 RK4 steps)
constexpr int WPB = 4;    // waves (= batch elements) per block

__device__ __forceinline__ uint32_t dpp_xor1_u(uint32_t v) {   // quad_perm [1,0,3,2]
    return (uint32_t)__builtin_amdgcn_update_dpp(0, (int)v, 0xB1, 0xF, 0xF, true);
}
__device__ __forceinline__ uint32_t dpp_xor2_u(uint32_t v) {   // quad_perm [2,3,0,1]
    return (uint32_t)__builtin_amdgcn_update_dpp(0, (int)v, 0x4E, 0xF, 0xF, true);
}
// acc += dot4(i8x4, i8x4) — signed 8-bit dot product, int32 accumulate.
__device__ __forceinline__ int dot4(int acc, uint32_t e, uint32_t x) {
#if __has_builtin(__builtin_amdgcn_sdot4)
    return __builtin_amdgcn_sdot4((int)e, (int)x, acc, false);
#else
    asm("v_dot4_i32_i8 %0, %1, %2, %0" : "+v"(acc) : "v"(e), "v"(x));
    return acc;
#endif
}

// f(xt) = xt * (r - xt + E@xt); broadcast via i8-packed LDS.
// Order-only barrier between write and reads: per-wave DS FIFO guarantees
// the reads observe the write (R20-verified on gfx950); compiler inserts
// minimal lgkmcnt for the read returns.
#define FEVAL(XT, RES)                                                        \
    do {                                                                      \
        const float xt_ = (XT);                                               \
        const uint32_t q_  = (uint32_t)fmaf(xt_, 127.0f, 0.5f);               \
        const uint32_t t1_ = q_  | (dpp_xor1_u(q_)  << 8);                    \
        const uint32_t t2_ = t1_ | (dpp_xor2_u(t1_) << 16);                   \
        wbuf[waddr] = t2_;                                /* 1 ds_write */    \
        asm volatile("" ::: "memory");                    /* order only  */   \
        int a0 = 0, a1 = 0, a2 = 0, a3 = 0;                                   \
        _Pragma("unroll")                                                     \
        for (int J = 0; J < 4; ++J) {                     /* 4 uniform b128 */\
            const uint4 v_ = *reinterpret_cast<const uint4*>(wbuf + 4 * J);   \
            a0 = dot4(a0, eq[4 * J + 0], v_.x);                               \
            a1 = dot4(a1, eq[4 * J + 1], v_.y);                               \
            a2 = dot4(a2, eq[4 * J + 2], v_.z);                               \
            a3 = dot4(a3, eq[4 * J + 3], v_.w);                               \
        }                                                                     \
        const float cp_ = (float)((a0 + a1) + (a2 + a3)) * scl;               \
        RES = xt_ * ((ri + cp_) - xt_);                                       \
    } while (0)

// Per-iteration residency pin (R14-verified recipe).
#define PIN8(B)                                                               \
    asm volatile("" : "+v"(eq[B + 0]), "+v"(eq[B + 1]), "+v"(eq[B + 2]),      \
                      "+v"(eq[B + 3]), "+v"(eq[B + 4]), "+v"(eq[B + 5]),      \
                      "+v"(eq[B + 6]), "+v"(eq[B + 7]))

__global__ __launch_bounds__(WPB * 64)
__attribute__((amdgpu_waves_per_eu(2, 2)))
void glv_rk4_kernel(const float* __restrict__ x0,
                    const float* __restrict__ r,
                    const float* __restrict__ A,
                    const float* __restrict__ tgrid,
                    float* __restrict__ out)
{
    const int lane = threadIdx.x & 63;
    const int wid  = threadIdx.x >> 6;
    const int b    = blockIdx.x * WPB + wid;   // batch element for this wave

    // Per-wave broadcast buffer: 16 real dwords (64 x i8) + 48 shadow.
    __shared__ uint32_t xq[WPB][64];
    uint32_t* const wbuf = &xq[wid][0];
    const int waddr = (lane >> 2) + (lane & 3) * 16;  // shadow for lane%4 != 0

    // E = A + I, row `lane`, quantized i8 with per-row scale -> 16 VGPRs.
    float ev[D];
    float rowmax = 1e-30f;
#pragma unroll
    for (int j = 0; j < D; j += 4) {
        const float4 v = *reinterpret_cast<const float4*>(A + lane * D + j);
        ev[j + 0] = v.x + ((j + 0) == lane ? 1.0f : 0.0f);
        ev[j + 1] = v.y + ((j + 1) == lane ? 1.0f : 0.0f);
        ev[j + 2] = v.z + ((j + 2) == lane ? 1.0f : 0.0f);
        ev[j + 3] = v.w + ((j + 3) == lane ? 1.0f : 0.0f);
        rowmax = fmaxf(rowmax, fmaxf(fmaxf(fabsf(ev[j]), fabsf(ev[j + 1])),
                                     fmaxf(fabsf(ev[j + 2]), fabsf(ev[j + 3]))));
    }
    const float qinv = 127.0f / rowmax;
    const float scl  = rowmax * (1.0f / (127.0f * 127.0f));

    uint32_t eq[D / 4];
#pragma unroll
    for (int J = 0; J < D / 4; ++J) {
        const int b0 = (int)rintf(ev[4 * J + 0] * qinv);
        const int b1 = (int)rintf(ev[4 * J + 1] * qinv);
        const int b2 = (int)rintf(ev[4 * J + 2] * qinv);
        const int b3 = (int)rintf(ev[4 * J + 3] * qinv);
        eq[J] = (uint32_t)(b0 & 0xFF) | ((uint32_t)(b1 & 0xFF) << 8) |
                ((uint32_t)(b2 & 0xFF) << 16) | ((uint32_t)(b3 & 0xFF) << 24);
    }

    const float ri = r[lane];
    const float dt = tgrid[1] - tgrid[0];
    const float h2 = 0.5f * dt;
    const float h6 = dt * (1.0f / 6.0f);

    float x = x0[(size_t)b * D + lane];

    float* o = out + (size_t)b * NT * D + lane;
    *o = x; o += D;                            // t = 0 is x0

    for (int t = 1; t < NT; ++t) {
        PIN8(0); PIN8(8);                      // keep eq in arch VGPRs
        float k1, k2, k3, k4;
        FEVAL(x, k1);
        FEVAL(fmaf(h2, k1, x), k2);
        FEVAL(fmaf(h2, k2, x), k3);
        FEVAL(fmaf(dt, k3, x), k4);
        x = fmaf(h6, (k1 + k4) + 2.0f * (k2 + k3), x);
        *o = x; o += D;                        // coalesced 256 B/wave store
    }
}

extern "C" void kernel_launch(void* const* d_in, const int* in_sizes, int n_in,
                              void* d_out, int out_size, void* d_ws, size_t ws_size,
                              hipStream_t stream) {
    const float* x0    = (const float*)d_in[0];
    const float* r     = (const float*)d_in[1];
    const float* A     = (const float*)d_in[2];
    const float* tgrid = (const float*)d_in[3];
    float* out         = (float*)d_out;

    const int batch = in_sizes[0] / D;          // 2048
    dim3 grid(batch / WPB);                     // 512 blocks
    dim3 block(WPB * 64);                       // 256 threads = 4 waves

    glv_rk4_kernel<<<grid, block, 0, stream>>>(x0, r, A, tgrid, out);
}